// Round 5
// baseline (445.545 us; speedup 1.0000x reference)
//
#include <hip/hip_runtime.h>
#include <math.h>

#define NCAPS 8
#define DD    16
#define D     128
#define M     32
#define ROUTIT 6
#define CUT   5

__device__ __forceinline__ float wred16_sum(float v) {
    v += __shfl_xor(v, 1);
    v += __shfl_xor(v, 2);
    v += __shfl_xor(v, 4);
    v += __shfl_xor(v, 8);
    return v;
}

// Pin a float4 into VGPRs: empty asm marks the values as modified, so the
// compiler cannot sink/rematerialize the producing loads into the loop.
__device__ __forceinline__ void pin4(float4& f) {
    asm volatile("" : "+v"(f.x), "+v"(f.y), "+v"(f.z), "+v"(f.w));
}

// ---------------------------------------------------------------- init
__global__ void init_kernel(float* xc0, float* xc1, int n) {
    int t = threadIdx.x;
    if (t < D) {
        xc0[(size_t)n * D + t] = 0.f;   // dummy row n = 0
        xc1[(size_t)n * D + t] = 0.f;
    }
}

// ---------------------------------------------------------------- PCA GEMM
// h[n,128] = x[n,500] @ w[500,128] + bias   (BM=32, BN=128, BK=20, 4x4 microtile)
__global__ __launch_bounds__(256) void pca_gemm(
        const float* __restrict__ x, const float* __restrict__ w,
        const float* __restrict__ bias, float* __restrict__ h,
        int n, int nfeat) {
    __shared__ float xs[20][36];    // [kk][r], pad keeps float4 alignment
    __shared__ float ws[20][128];   // [kk][col]
    const int tid = threadIdx.x;
    const int cg = tid & 31;        // col group: cols cg*4 .. +3
    const int rg = tid >> 5;        // row group: rows rg*4 .. +3
    const int row0 = blockIdx.x * 32;
    float acc[4][4] = {};
    for (int k0 = 0; k0 < nfeat; k0 += 20) {
#pragma unroll
        for (int i = 0; i < 3; ++i) {           // 640 elems of x tile
            int l = tid + i * 256;
            if (l < 640) {
                int r = l / 20, kk = l - r * 20;
                int row = row0 + r;
                xs[kk][r] = (row < n) ? x[(size_t)row * nfeat + k0 + kk] : 0.f;
            }
        }
#pragma unroll
        for (int i = 0; i < 10; ++i) {          // 2560 elems of w tile
            int l = tid + i * 256;
            int kk = l >> 7, col = l & 127;
            ws[kk][col] = w[(size_t)(k0 + kk) * 128 + col];
        }
        __syncthreads();
#pragma unroll
        for (int kk = 0; kk < 20; ++kk) {
            float4 a = *(const float4*)&xs[kk][rg * 4];
            float4 b = *(const float4*)&ws[kk][cg * 4];
            float av[4] = {a.x, a.y, a.z, a.w};
            float bv[4] = {b.x, b.y, b.z, b.w};
#pragma unroll
            for (int i = 0; i < 4; ++i)
#pragma unroll
                for (int j = 0; j < 4; ++j) acc[i][j] += av[i] * bv[j];
        }
        __syncthreads();
    }
#pragma unroll
    for (int i = 0; i < 4; ++i) {
        int row = row0 + rg * 4 + i;
        if (row < n) {
#pragma unroll
            for (int j = 0; j < 4; ++j)
                h[(size_t)row * 128 + cg * 4 + j] = acc[i][j] + bias[cg * 4 + j];
        }
    }
}

// ---------------------------------------------------------------- attn loss + relu-normalize prep
__global__ __launch_bounds__(256) void attn_prep(
        const float* __restrict__ h, const float* __restrict__ ln_g,
        const float* __restrict__ ln_b, const float* __restrict__ w_qs,
        const float* __restrict__ w_ks, float* __restrict__ xc0,
        float* __restrict__ partial, int n) {
    __shared__ float wq[256], wk[256];
    __shared__ float qn[2][8][17], hh[2][8][17], qq[2][8][17], kks[2][8][17];
    __shared__ float red[4];
    const int t = threadIdx.x;
    const int half = t >> 7, tl = t & 127;
    const int k = tl >> 4, c = tl & 15;
    const int v = blockIdx.x * 2 + half;
    wq[t] = w_qs[t];
    wk[t] = w_ks[t];
    float hv = 0.f;
    if (v < n) {
        hv = h[(size_t)v * D + tl];
        float mu = wred16_sum(hv) * (1.f / 16.f);
        float dv = hv - mu;
        float var = wred16_sum(dv * dv) * (1.f / 16.f);
        float rstd = rsqrtf(var + 1e-6f);
        qn[half][k][c] = dv * rstd * ln_g[c] + ln_b[c];
        hh[half][k][c] = hv;
    }
    __syncthreads();
    if (v < n) {
        float q = 0.f, kv = 0.f;
#pragma unroll
        for (int cp = 0; cp < 16; ++cp) {
            q  += qn[half][k][cp] * wq[cp * 16 + c];
            kv += hh[half][k][cp] * wk[cp * 16 + c];
        }
        qq[half][k][c]  = q * 0.25f;   // 1/sqrt(16)
        kks[half][k][c] = kv;
    }
    __syncthreads();
    float offd = 0.f;
    if (v < n && tl < 64) {
        int ki = tl >> 3, j = tl & 7;
        float s = 0.f;
#pragma unroll
        for (int cc = 0; cc < 16; ++cc) s += qq[half][ki][cc] * kks[half][j][cc];
        float mx = s;
        mx = fmaxf(mx, __shfl_xor(mx, 1));
        mx = fmaxf(mx, __shfl_xor(mx, 2));
        mx = fmaxf(mx, __shfl_xor(mx, 4));
        float e = __expf(s - mx);
        float se = e;
        se += __shfl_xor(se, 1);
        se += __shfl_xor(se, 2);
        se += __shfl_xor(se, 4);
        float attn = e / se;
        offd = (j != ki) ? attn : 0.f;
    }
    offd += __shfl_xor(offd, 1);
    offd += __shfl_xor(offd, 2);
    offd += __shfl_xor(offd, 4);
    offd += __shfl_xor(offd, 8);
    offd += __shfl_xor(offd, 16);
    offd += __shfl_xor(offd, 32);
    int lane = t & 63, wid = t >> 6;
    if (lane == 0) red[wid] = offd;
    __syncthreads();
    if (t == 0) partial[blockIdx.x] = red[0] + red[1] + red[2] + red[3];
    if (v < n) {
        float r = fmaxf(hv, 0.f);
        float ss = wred16_sum(r * r);
        xc0[(size_t)v * D + tl] = r / fmaxf(sqrtf(ss), 1e-12f);
    }
}

// ---------------------------------------------------------------- partial-sum reduce
__global__ __launch_bounds__(256) void reduce_kernel(
        const float* __restrict__ partial, float* __restrict__ acc, int npart) {
    __shared__ float red[4];
    const int t = threadIdx.x;
    float s = 0.f;
    for (int i = t; i < npart; i += 256) s += partial[i];
    s += __shfl_xor(s, 1);  s += __shfl_xor(s, 2);
    s += __shfl_xor(s, 4);  s += __shfl_xor(s, 8);
    s += __shfl_xor(s, 16); s += __shfl_xor(s, 32);
    if ((t & 63) == 0) red[t >> 6] = s;
    __syncthreads();
    if (t == 0) acc[0] = red[0] + red[1] + red[2] + red[3];
}

// ---------------------------------------------------------------- routing (one block per node)
// z strictly register-resident: zr/zu pinned via inline asm so the compiler
// cannot sink the gathers into the iteration loop (round-4 showed VGPR=44 <
// the 48 needed -> per-iteration L2 re-fetch was the bottleneck).
template <bool LAST>
__global__ __launch_bounds__(256, 4) void routing_kernel(
        const float* __restrict__ xc,   // (n+1)*128, normalized, row n = 0
        const int* __restrict__ nb,     // n*32
        float* __restrict__ out,        // LAST ? u1 : xc_next rows [0,n)
        int* __restrict__ amax, int n) {
    __shared__ alignas(16) float u_s[NCAPS * 20];   // u[k][c] at k*20+c
    __shared__ alignas(16) float pT[NCAPS * 36];    // pT[k][m]
    __shared__ alignas(16) float redz[D];           // cross-wave reduce bounce
    __shared__ int srcs[M];
    const int t = threadIdx.x;
    const int m = t >> 3, k = t & 7;                // p-step mapping
    const int q = t & 31, mg = t >> 5;              // u-step mapping (t<128)
    const int v = blockIdx.x;

    if (t < M) {
        int nbv = nb[(size_t)v * M + t];
        srcs[t] = (nbv < 0) ? n : nbv;
    }
    __syncthreads();

    // ---- p-step rows: z[m][k][0..15] in registers (pinned)
    const float4* zsrc = (const float4*)(xc + (size_t)srcs[m] * D + k * DD);
    float4 z0 = zsrc[0], z1 = zsrc[1], z2 = zsrc[2], z3 = zsrc[3];
    pin4(z0); pin4(z1); pin4(z2); pin4(z3);
    float zr[16] = {z0.x, z0.y, z0.z, z0.w, z1.x, z1.y, z1.z, z1.w,
                    z2.x, z2.y, z2.z, z2.w, z3.x, z3.y, z3.z, z3.w};
    // ---- u-step cols: z[mg*8+j][q*4..q*4+3] in registers (t<128, pinned)
    float4 zu[8];
    if (t < 128) {
#pragma unroll
        for (int j = 0; j < 8; ++j) {
            zu[j] = ((const float4*)(xc + (size_t)srcs[mg * 8 + j] * D))[q];
            pin4(zu[j]);
        }
    }
    float4 x3f4 = make_float4(0.f, 0.f, 0.f, 0.f);
    if (t < 32) {
        x3f4 = ((const float4*)(xc + (size_t)v * D))[q];
        pin4(x3f4);
    }

    float p0, p1, p2, p3;   // u-step partials (t<128), totals live in t<32

    // ---- it 0: p uniform = 1/8 (pure register math)
    if (t < 128) {
        p0 = p1 = p2 = p3 = 0.f;
#pragma unroll
        for (int j = 0; j < 8; ++j) {
            p0 += zu[j].x; p1 += zu[j].y; p2 += zu[j].z; p3 += zu[j].w;
        }
        p0 += __shfl_xor(p0, 32); p1 += __shfl_xor(p1, 32);
        p2 += __shfl_xor(p2, 32); p3 += __shfl_xor(p3, 32);
        if (t >= 64 && t < 96)
            ((float4*)redz)[q] = make_float4(p0, p1, p2, p3);
    }
    __syncthreads();
    if (t < 32) {
        float4 r = ((const float4*)redz)[q];
        float a0 = (p0 + r.x) * 0.125f + x3f4.x;
        float a1 = (p1 + r.y) * 0.125f + x3f4.y;
        float a2 = (p2 + r.z) * 0.125f + x3f4.z;
        float a3 = (p3 + r.w) * 0.125f + x3f4.w;
        float ss = a0 * a0 + a1 * a1 + a2 * a2 + a3 * a3;
        ss += __shfl_xor(ss, 1); ss += __shfl_xor(ss, 2);
        float inv = 1.f / fmaxf(sqrtf(ss), 1e-12f);
        *(float4*)&u_s[(q >> 2) * 20 + (q & 3) * 4] =
            make_float4(a0 * inv, a1 * inv, a2 * inv, a3 * inv);
    }
    __syncthreads();

    for (int it = 1; it < ROUTIT; ++it) {
        // ---- p-step (all 256 threads, one (m,k) each)
        const float4* uf = (const float4*)&u_s[k * 20];   // conflict-free broadcast
        float4 u0 = uf[0], u1 = uf[1], u2 = uf[2], u3 = uf[3];
        float p = zr[0] * u0.x + zr[1] * u0.y + zr[2] * u0.z + zr[3] * u0.w
                + zr[4] * u1.x + zr[5] * u1.y + zr[6] * u1.z + zr[7] * u1.w
                + zr[8] * u2.x + zr[9] * u2.y + zr[10] * u2.z + zr[11] * u2.w
                + zr[12] * u3.x + zr[13] * u3.y + zr[14] * u3.z + zr[15] * u3.w;
        if (LAST && it == ROUTIT - 1) {
            // argmax over k (softmax monotone; first-index tiebreak like jnp.argmax)
            float bv = p; int bi = k;
#pragma unroll
            for (int msk = 1; msk <= 4; msk <<= 1) {
                float ov = __shfl_xor(bv, msk);
                int   oi = __shfl_xor(bi, msk);
                if (ov > bv || (ov == bv && oi < bi)) { bv = ov; bi = oi; }
            }
            if (k == 0) amax[(size_t)v * M + m] = bi;
        }
        // |p| <= 1 (u unit-norm, z rows unit-norm-or-zero) -> max-free softmax
        float e = __expf(p);
        float se = e;
        se += __shfl_xor(se, 1);
        se += __shfl_xor(se, 2);
        se += __shfl_xor(se, 4);
        pT[k * 36 + m] = e / se;
        __syncthreads();
        // ---- u-step A (t<128): weighted column sums from registers
        if (t < 128) {
            const int k2 = q >> 2;
            float4 pA = *(const float4*)&pT[k2 * 36 + mg * 8];
            float4 pB = *(const float4*)&pT[k2 * 36 + mg * 8 + 4];
            float pk[8] = {pA.x, pA.y, pA.z, pA.w, pB.x, pB.y, pB.z, pB.w};
            p0 = p1 = p2 = p3 = 0.f;
#pragma unroll
            for (int j = 0; j < 8; ++j) {
                p0 += zu[j].x * pk[j]; p1 += zu[j].y * pk[j];
                p2 += zu[j].z * pk[j]; p3 += zu[j].w * pk[j];
            }
            p0 += __shfl_xor(p0, 32); p1 += __shfl_xor(p1, 32);
            p2 += __shfl_xor(p2, 32); p3 += __shfl_xor(p3, 32);
            if (t >= 64 && t < 96)
                ((float4*)redz)[q] = make_float4(p0, p1, p2, p3);
        }
        __syncthreads();
        // ---- u-step B (t<32): finalize
        if (t < 32) {
            float4 r = ((const float4*)redz)[q];
            float a0 = p0 + r.x + x3f4.x;
            float a1 = p1 + r.y + x3f4.y;
            float a2 = p2 + r.z + x3f4.z;
            float a3 = p3 + r.w + x3f4.w;
            if (it < ROUTIT - 1) {
                float ss = a0 * a0 + a1 * a1 + a2 * a2 + a3 * a3;
                ss += __shfl_xor(ss, 1); ss += __shfl_xor(ss, 2);
                float inv = 1.f / fmaxf(sqrtf(ss), 1e-12f);
                *(float4*)&u_s[(q >> 2) * 20 + (q & 3) * 4] =
                    make_float4(a0 * inv, a1 * inv, a2 * inv, a3 * inv);
            } else if (LAST) {
                ((float4*)(out + (size_t)v * D))[q] = make_float4(a0, a1, a2, a3);
            } else {
                float r0 = fmaxf(a0, 0.f), r1 = fmaxf(a1, 0.f);
                float r2 = fmaxf(a2, 0.f), r3 = fmaxf(a3, 0.f);
                float ss = r0 * r0 + r1 * r1 + r2 * r2 + r3 * r3;
                ss += __shfl_xor(ss, 1); ss += __shfl_xor(ss, 2);
                float inv = 1.f / fmaxf(sqrtf(ss), 1e-12f);
                ((float4*)(out + (size_t)v * D))[q] =
                    make_float4(r0 * inv, r1 * inv, r2 * inv, r3 * inv);
            }
        }
        if (it < ROUTIT - 1) __syncthreads();
    }
}

// ---------------------------------------------------------------- meta gather + MLP + log_softmax
__global__ __launch_bounds__(256) void meta_kernel(
        const float* __restrict__ u1, const float* __restrict__ xc1,
        const int* __restrict__ nb, const int* __restrict__ amax,
        const float* __restrict__ mlp_w, const float* __restrict__ mlp_b,
        const float* __restrict__ attn_acc, float* __restrict__ d_out, int n) {
    __shared__ float Wl[128 * 16];
    __shared__ float accs[16][132];
    const int t = threadIdx.x;
#pragma unroll
    for (int i = 0; i < 8; ++i) Wl[t + i * 256] = mlp_w[t + i * 256];
    const int g = t >> 4, c = t & 15;
    const int v = blockIdx.x * 16 + g;
    if (blockIdx.x == 0 && t == 0)
        d_out[(size_t)n * 16] = attn_acc[0] * (1.f / (56.f * (float)n));
    if (v < n) {
#pragma unroll
        for (int i = 0; i < 8; ++i) accs[g][i * 16 + c] = 0.f;
        for (int a = 0; a < CUT; ++a) {
            int w = nb[(size_t)v * M + a];
            if (w < 0) continue;
            int i = amax[(size_t)v * M + a];   // first-hop capsule
            float s = 0.f;
#pragma unroll
            for (int b = 0; b < CUT; ++b) {
                int idx = nb[(size_t)w * M + b];
                int jj  = amax[(size_t)w * M + b];
                int im  = (idx < 0) ? n : idx;   // row n = zeros
                s += xc1[(size_t)im * D + jj * DD + c];
            }
            accs[g][i * 16 + c] += s;
        }
#pragma unroll
        for (int i = 0; i < 8; ++i) {
            float meta = u1[(size_t)v * D + i * 16 + c] + accs[g][i * 16 + c] * (1.f / 25.f);
            accs[g][i * 16 + c] = fmaxf(meta, 0.f);   // relu, staged for MLP
        }
    }
    __syncthreads();
    if (v < n) {
        float o = mlp_b[c];
#pragma unroll
        for (int dd = 0; dd < 128; ++dd) o += accs[g][dd] * Wl[dd * 16 + c];
        float mx = o;
        mx = fmaxf(mx, __shfl_xor(mx, 1));
        mx = fmaxf(mx, __shfl_xor(mx, 2));
        mx = fmaxf(mx, __shfl_xor(mx, 4));
        mx = fmaxf(mx, __shfl_xor(mx, 8));
        float e = __expf(o - mx);
        float se = wred16_sum(e);
        float ls = (o - mx) - logf(se);
        d_out[(size_t)v * 16 + c] = ls;
        d_out[(size_t)n * 16 + 1 + (size_t)v * 16 + c] = o;
    }
}

// ---------------------------------------------------------------- launch
extern "C" void kernel_launch(void* const* d_in, const int* in_sizes, int n_in,
                              void* d_out, int out_size, void* d_ws, size_t ws_size,
                              hipStream_t stream) {
    const float* x     = (const float*)d_in[0];
    const int*   nb    = (const int*)d_in[1];
    const float* pca_w = (const float*)d_in[2];
    const float* pca_b = (const float*)d_in[3];
    const float* ln_g  = (const float*)d_in[4];
    const float* ln_b  = (const float*)d_in[5];
    const float* w_qs  = (const float*)d_in[6];
    const float* w_ks  = (const float*)d_in[7];
    const float* mlp_w = (const float*)d_in[8];
    const float* mlp_b = (const float*)d_in[9];
    float* out = (float*)d_out;

    const int d = 128;
    const int nfeat = in_sizes[2] / d;      // 500
    const int n = in_sizes[0] / nfeat;      // 20000
    const int npart = (n + 1) / 2;          // attn_prep block count

    float* bufA = (float*)d_ws;                       // n*128   : h, later u1
    float* bufB = bufA + (size_t)n * d;               // (n+1)*128 : xc0; amax overlays (xc0 dead)
    float* bufC = bufB + (size_t)(n + 1) * d;         // (n+1)*128 : xc1
    float* acc  = bufC + (size_t)(n + 1) * d;         // 1 float : attn loss sum
    int* amax = (int*)bufB;
    // attn partials overlay the head of bufC: consumed by reduce_kernel
    // before routing<false> writes bufC; row n untouched.
    float* partial = bufC;

    init_kernel<<<1, 256, 0, stream>>>(bufB, bufC, n);
    pca_gemm<<<(n + 31) / 32, 256, 0, stream>>>(x, pca_w, pca_b, bufA, n, nfeat);
    attn_prep<<<npart, 256, 0, stream>>>(bufA, ln_g, ln_b, w_qs, w_ks, bufB, partial, n);
    reduce_kernel<<<1, 256, 0, stream>>>(partial, acc, npart);
    routing_kernel<false><<<n, 256, 0, stream>>>(bufB, nb, bufC, nullptr, n);
    routing_kernel<true><<<n, 256, 0, stream>>>(bufC, nb, bufA, amax, n);
    meta_kernel<<<(n + 15) / 16, 256, 0, stream>>>(bufA, bufC, nb, amax, mlp_w, mlp_b, acc, out, n);
}

// Round 6
// 390.350 us; speedup vs baseline: 1.1414x; 1.1414x over previous
//
#include <hip/hip_runtime.h>
#include <math.h>

#define NCAPS 8
#define DD    16
#define D     128
#define M     32
#define ROUTIT 6
#define CUT   5

__device__ __forceinline__ float wred16_sum(float v) {
    v += __shfl_xor(v, 1);
    v += __shfl_xor(v, 2);
    v += __shfl_xor(v, 4);
    v += __shfl_xor(v, 8);
    return v;
}

// Pin a float4 into VGPRs: empty asm marks the values as modified, so the
// compiler cannot sink/rematerialize the producing loads into the loop.
__device__ __forceinline__ void pin4(float4& f) {
    asm volatile("" : "+v"(f.x), "+v"(f.y), "+v"(f.z), "+v"(f.w));
}

// ---------------------------------------------------------------- init
__global__ void init_kernel(float* xc0, float* xc1, int n) {
    int t = threadIdx.x;
    if (t < D) {
        xc0[(size_t)n * D + t] = 0.f;   // dummy row n = 0
        xc1[(size_t)n * D + t] = 0.f;
    }
}

// ---------------------------------------------------------------- PCA GEMM
// h[n,128] = x[n,500] @ w[500,128] + bias   (BM=32, BN=128, BK=20, 4x4 microtile)
__global__ __launch_bounds__(256) void pca_gemm(
        const float* __restrict__ x, const float* __restrict__ w,
        const float* __restrict__ bias, float* __restrict__ h,
        int n, int nfeat) {
    __shared__ float xs[20][36];    // [kk][r], pad keeps float4 alignment
    __shared__ float ws[20][128];   // [kk][col]
    const int tid = threadIdx.x;
    const int cg = tid & 31;        // col group: cols cg*4 .. +3
    const int rg = tid >> 5;        // row group: rows rg*4 .. +3
    const int row0 = blockIdx.x * 32;
    float acc[4][4] = {};
    for (int k0 = 0; k0 < nfeat; k0 += 20) {
#pragma unroll
        for (int i = 0; i < 3; ++i) {           // 640 elems of x tile
            int l = tid + i * 256;
            if (l < 640) {
                int r = l / 20, kk = l - r * 20;
                int row = row0 + r;
                xs[kk][r] = (row < n) ? x[(size_t)row * nfeat + k0 + kk] : 0.f;
            }
        }
#pragma unroll
        for (int i = 0; i < 10; ++i) {          // 2560 elems of w tile
            int l = tid + i * 256;
            int kk = l >> 7, col = l & 127;
            ws[kk][col] = w[(size_t)(k0 + kk) * 128 + col];
        }
        __syncthreads();
#pragma unroll
        for (int kk = 0; kk < 20; ++kk) {
            float4 a = *(const float4*)&xs[kk][rg * 4];
            float4 b = *(const float4*)&ws[kk][cg * 4];
            float av[4] = {a.x, a.y, a.z, a.w};
            float bv[4] = {b.x, b.y, b.z, b.w};
#pragma unroll
            for (int i = 0; i < 4; ++i)
#pragma unroll
                for (int j = 0; j < 4; ++j) acc[i][j] += av[i] * bv[j];
        }
        __syncthreads();
    }
#pragma unroll
    for (int i = 0; i < 4; ++i) {
        int row = row0 + rg * 4 + i;
        if (row < n) {
#pragma unroll
            for (int j = 0; j < 4; ++j)
                h[(size_t)row * 128 + cg * 4 + j] = acc[i][j] + bias[cg * 4 + j];
        }
    }
}

// ---------------------------------------------------------------- attn loss + relu-normalize prep
__global__ __launch_bounds__(256) void attn_prep(
        const float* __restrict__ h, const float* __restrict__ ln_g,
        const float* __restrict__ ln_b, const float* __restrict__ w_qs,
        const float* __restrict__ w_ks, float* __restrict__ xc0,
        float* __restrict__ partial, int n) {
    __shared__ float wq[256], wk[256];
    __shared__ float qn[2][8][17], hh[2][8][17], qq[2][8][17], kks[2][8][17];
    __shared__ float red[4];
    const int t = threadIdx.x;
    const int half = t >> 7, tl = t & 127;
    const int k = tl >> 4, c = tl & 15;
    const int v = blockIdx.x * 2 + half;
    wq[t] = w_qs[t];
    wk[t] = w_ks[t];
    float hv = 0.f;
    if (v < n) {
        hv = h[(size_t)v * D + tl];
        float mu = wred16_sum(hv) * (1.f / 16.f);
        float dv = hv - mu;
        float var = wred16_sum(dv * dv) * (1.f / 16.f);
        float rstd = rsqrtf(var + 1e-6f);
        qn[half][k][c] = dv * rstd * ln_g[c] + ln_b[c];
        hh[half][k][c] = hv;
    }
    __syncthreads();
    if (v < n) {
        float q = 0.f, kv = 0.f;
#pragma unroll
        for (int cp = 0; cp < 16; ++cp) {
            q  += qn[half][k][cp] * wq[cp * 16 + c];
            kv += hh[half][k][cp] * wk[cp * 16 + c];
        }
        qq[half][k][c]  = q * 0.25f;   // 1/sqrt(16)
        kks[half][k][c] = kv;
    }
    __syncthreads();
    float offd = 0.f;
    if (v < n && tl < 64) {
        int ki = tl >> 3, j = tl & 7;
        float s = 0.f;
#pragma unroll
        for (int cc = 0; cc < 16; ++cc) s += qq[half][ki][cc] * kks[half][j][cc];
        float mx = s;
        mx = fmaxf(mx, __shfl_xor(mx, 1));
        mx = fmaxf(mx, __shfl_xor(mx, 2));
        mx = fmaxf(mx, __shfl_xor(mx, 4));
        float e = __expf(s - mx);
        float se = e;
        se += __shfl_xor(se, 1);
        se += __shfl_xor(se, 2);
        se += __shfl_xor(se, 4);
        float attn = e / se;
        offd = (j != ki) ? attn : 0.f;
    }
    offd += __shfl_xor(offd, 1);
    offd += __shfl_xor(offd, 2);
    offd += __shfl_xor(offd, 4);
    offd += __shfl_xor(offd, 8);
    offd += __shfl_xor(offd, 16);
    offd += __shfl_xor(offd, 32);
    int lane = t & 63, wid = t >> 6;
    if (lane == 0) red[wid] = offd;
    __syncthreads();
    if (t == 0) partial[blockIdx.x] = red[0] + red[1] + red[2] + red[3];
    if (v < n) {
        float r = fmaxf(hv, 0.f);
        float ss = wred16_sum(r * r);
        xc0[(size_t)v * D + tl] = r / fmaxf(sqrtf(ss), 1e-12f);
    }
}

// ---------------------------------------------------------------- partial-sum reduce
__global__ __launch_bounds__(256) void reduce_kernel(
        const float* __restrict__ partial, float* __restrict__ acc, int npart) {
    __shared__ float red[4];
    const int t = threadIdx.x;
    float s = 0.f;
    for (int i = t; i < npart; i += 256) s += partial[i];
    s += __shfl_xor(s, 1);  s += __shfl_xor(s, 2);
    s += __shfl_xor(s, 4);  s += __shfl_xor(s, 8);
    s += __shfl_xor(s, 16); s += __shfl_xor(s, 32);
    if ((t & 63) == 0) red[t >> 6] = s;
    __syncthreads();
    if (t == 0) acc[0] = red[0] + red[1] + red[2] + red[3];
}

// ---------------------------------------------------------------- routing (one block per node)
// z split: p-step fragment zr[16] lives in registers (16 VGPRs, pinned after
// the LDS store so it can't be rematerialized from global OR LDS); full z
// staged once into LDS (132-float rows) for the u-step's per-iteration reads.
// R4 showed re-fetching z from L1/L2 every iteration (~16KB/iter/block) was
// the bottleneck; R5 showed the allocator spills if we pin 48+ VGPRs.
template <bool LAST>
__global__ __launch_bounds__(256) void routing_kernel(
        const float* __restrict__ xc,   // (n+1)*128, normalized, row n = 0
        const int* __restrict__ nb,     // n*32
        float* __restrict__ out,        // LAST ? u1 : xc_next rows [0,n)
        int* __restrict__ amax, int n) {
    __shared__ alignas(16) float zs[M][132];        // z rows, +4 pad
    __shared__ alignas(16) float u_s[NCAPS * 20];   // u[k][c] at k*20+c
    __shared__ alignas(16) float pT[NCAPS * 36];    // pT[k][m]
    __shared__ alignas(16) float redz[D];           // cross-wave reduce bounce
    __shared__ int srcs[M];
    const int t = threadIdx.x;
    const int m = t >> 3, k = t & 7;                // p-step mapping
    const int q = t & 31, mg = t >> 5;              // u-step mapping (t<128)
    const int v = blockIdx.x;

    if (t < M) {
        int nbv = nb[(size_t)v * M + t];
        srcs[t] = (nbv < 0) ? n : nbv;
    }
    __syncthreads();

    // ---- gather z once; stage to LDS (u-step) and keep p-fragment in regs
    const float4* zsrc = (const float4*)(xc + (size_t)srcs[m] * D + k * DD);
    float4 z0 = zsrc[0], z1 = zsrc[1], z2 = zsrc[2], z3 = zsrc[3];
    float4* zl = (float4*)&zs[m][k * DD];
    zl[0] = z0; zl[1] = z1; zl[2] = z2; zl[3] = z3;
    pin4(z0); pin4(z1); pin4(z2); pin4(z3);   // after store: opaque, reg-only
    float zr[16] = {z0.x, z0.y, z0.z, z0.w, z1.x, z1.y, z1.z, z1.w,
                    z2.x, z2.y, z2.z, z2.w, z3.x, z3.y, z3.z, z3.w};
    float4 x3f4 = make_float4(0.f, 0.f, 0.f, 0.f);
    if (t < 32) {
        x3f4 = ((const float4*)(xc + (size_t)v * D))[q];
        pin4(x3f4);
    }
    __syncthreads();

    float p0, p1, p2, p3;   // u-step partials (t<128), totals live in t<32

    // ---- it 0: p uniform = 1/8
    if (t < 128) {
        p0 = p1 = p2 = p3 = 0.f;
#pragma unroll
        for (int j = 0; j < 8; ++j) {
            float4 zz = *(const float4*)&zs[mg * 8 + j][q * 4];
            p0 += zz.x; p1 += zz.y; p2 += zz.z; p3 += zz.w;
        }
        p0 += __shfl_xor(p0, 32); p1 += __shfl_xor(p1, 32);
        p2 += __shfl_xor(p2, 32); p3 += __shfl_xor(p3, 32);
        if (t >= 64 && t < 96)
            ((float4*)redz)[q] = make_float4(p0, p1, p2, p3);
    }
    __syncthreads();
    if (t < 32) {
        float4 r = ((const float4*)redz)[q];
        float a0 = (p0 + r.x) * 0.125f + x3f4.x;
        float a1 = (p1 + r.y) * 0.125f + x3f4.y;
        float a2 = (p2 + r.z) * 0.125f + x3f4.z;
        float a3 = (p3 + r.w) * 0.125f + x3f4.w;
        float ss = a0 * a0 + a1 * a1 + a2 * a2 + a3 * a3;
        ss += __shfl_xor(ss, 1); ss += __shfl_xor(ss, 2);
        float inv = 1.f / fmaxf(sqrtf(ss), 1e-12f);
        *(float4*)&u_s[(q >> 2) * 20 + (q & 3) * 4] =
            make_float4(a0 * inv, a1 * inv, a2 * inv, a3 * inv);
    }
    __syncthreads();

    for (int it = 1; it < ROUTIT; ++it) {
        // ---- p-step (all 256 threads, one (m,k) each) — zr from registers
        const float4* uf = (const float4*)&u_s[k * 20];   // conflict-free broadcast
        float4 u0 = uf[0], u1 = uf[1], u2 = uf[2], u3 = uf[3];
        float p = zr[0] * u0.x + zr[1] * u0.y + zr[2] * u0.z + zr[3] * u0.w
                + zr[4] * u1.x + zr[5] * u1.y + zr[6] * u1.z + zr[7] * u1.w
                + zr[8] * u2.x + zr[9] * u2.y + zr[10] * u2.z + zr[11] * u2.w
                + zr[12] * u3.x + zr[13] * u3.y + zr[14] * u3.z + zr[15] * u3.w;
        if (LAST && it == ROUTIT - 1) {
            // argmax over k (softmax monotone; first-index tiebreak like jnp.argmax)
            float bv = p; int bi = k;
#pragma unroll
            for (int msk = 1; msk <= 4; msk <<= 1) {
                float ov = __shfl_xor(bv, msk);
                int   oi = __shfl_xor(bi, msk);
                if (ov > bv || (ov == bv && oi < bi)) { bv = ov; bi = oi; }
            }
            if (k == 0) amax[(size_t)v * M + m] = bi;
        }
        // |p| <= 1 (u unit-norm, z rows unit-norm-or-zero) -> max-free softmax
        float e = __expf(p);
        float se = e;
        se += __shfl_xor(se, 1);
        se += __shfl_xor(se, 2);
        se += __shfl_xor(se, 4);
        pT[k * 36 + m] = e / se;
        __syncthreads();
        // ---- u-step A (t<128): weighted column sums, z from LDS
        if (t < 128) {
            const int k2 = q >> 2;
            float4 pA = *(const float4*)&pT[k2 * 36 + mg * 8];
            float4 pB = *(const float4*)&pT[k2 * 36 + mg * 8 + 4];
            float pk[8] = {pA.x, pA.y, pA.z, pA.w, pB.x, pB.y, pB.z, pB.w};
            p0 = p1 = p2 = p3 = 0.f;
#pragma unroll
            for (int j = 0; j < 8; ++j) {
                float4 zz = *(const float4*)&zs[mg * 8 + j][q * 4];
                p0 += zz.x * pk[j]; p1 += zz.y * pk[j];
                p2 += zz.z * pk[j]; p3 += zz.w * pk[j];
            }
            p0 += __shfl_xor(p0, 32); p1 += __shfl_xor(p1, 32);
            p2 += __shfl_xor(p2, 32); p3 += __shfl_xor(p3, 32);
            if (t >= 64 && t < 96)
                ((float4*)redz)[q] = make_float4(p0, p1, p2, p3);
        }
        __syncthreads();
        // ---- u-step B (t<32): finalize
        if (t < 32) {
            float4 r = ((const float4*)redz)[q];
            float a0 = p0 + r.x + x3f4.x;
            float a1 = p1 + r.y + x3f4.y;
            float a2 = p2 + r.z + x3f4.z;
            float a3 = p3 + r.w + x3f4.w;
            if (it < ROUTIT - 1) {
                float ss = a0 * a0 + a1 * a1 + a2 * a2 + a3 * a3;
                ss += __shfl_xor(ss, 1); ss += __shfl_xor(ss, 2);
                float inv = 1.f / fmaxf(sqrtf(ss), 1e-12f);
                *(float4*)&u_s[(q >> 2) * 20 + (q & 3) * 4] =
                    make_float4(a0 * inv, a1 * inv, a2 * inv, a3 * inv);
            } else if (LAST) {
                ((float4*)(out + (size_t)v * D))[q] = make_float4(a0, a1, a2, a3);
            } else {
                float r0 = fmaxf(a0, 0.f), r1 = fmaxf(a1, 0.f);
                float r2 = fmaxf(a2, 0.f), r3 = fmaxf(a3, 0.f);
                float ss = r0 * r0 + r1 * r1 + r2 * r2 + r3 * r3;
                ss += __shfl_xor(ss, 1); ss += __shfl_xor(ss, 2);
                float inv = 1.f / fmaxf(sqrtf(ss), 1e-12f);
                ((float4*)(out + (size_t)v * D))[q] =
                    make_float4(r0 * inv, r1 * inv, r2 * inv, r3 * inv);
            }
        }
        if (it < ROUTIT - 1) __syncthreads();
    }
}

// ---------------------------------------------------------------- meta gather + MLP + log_softmax
__global__ __launch_bounds__(256) void meta_kernel(
        const float* __restrict__ u1, const float* __restrict__ xc1,
        const int* __restrict__ nb, const int* __restrict__ amax,
        const float* __restrict__ mlp_w, const float* __restrict__ mlp_b,
        const float* __restrict__ attn_acc, float* __restrict__ d_out, int n) {
    __shared__ float Wl[128 * 16];
    __shared__ float accs[16][132];
    const int t = threadIdx.x;
#pragma unroll
    for (int i = 0; i < 8; ++i) Wl[t + i * 256] = mlp_w[t + i * 256];
    const int g = t >> 4, c = t & 15;
    const int v = blockIdx.x * 16 + g;
    if (blockIdx.x == 0 && t == 0)
        d_out[(size_t)n * 16] = attn_acc[0] * (1.f / (56.f * (float)n));
    if (v < n) {
#pragma unroll
        for (int i = 0; i < 8; ++i) accs[g][i * 16 + c] = 0.f;
        for (int a = 0; a < CUT; ++a) {
            int w = nb[(size_t)v * M + a];
            if (w < 0) continue;
            int i = amax[(size_t)v * M + a];   // first-hop capsule
            float s = 0.f;
#pragma unroll
            for (int b = 0; b < CUT; ++b) {
                int idx = nb[(size_t)w * M + b];
                int jj  = amax[(size_t)w * M + b];
                int im  = (idx < 0) ? n : idx;   // row n = zeros
                s += xc1[(size_t)im * D + jj * DD + c];
            }
            accs[g][i * 16 + c] += s;
        }
#pragma unroll
        for (int i = 0; i < 8; ++i) {
            float meta = u1[(size_t)v * D + i * 16 + c] + accs[g][i * 16 + c] * (1.f / 25.f);
            accs[g][i * 16 + c] = fmaxf(meta, 0.f);   // relu, staged for MLP
        }
    }
    __syncthreads();
    if (v < n) {
        float o = mlp_b[c];
#pragma unroll
        for (int dd = 0; dd < 128; ++dd) o += accs[g][dd] * Wl[dd * 16 + c];
        float mx = o;
        mx = fmaxf(mx, __shfl_xor(mx, 1));
        mx = fmaxf(mx, __shfl_xor(mx, 2));
        mx = fmaxf(mx, __shfl_xor(mx, 4));
        mx = fmaxf(mx, __shfl_xor(mx, 8));
        float e = __expf(o - mx);
        float se = wred16_sum(e);
        float ls = (o - mx) - logf(se);
        d_out[(size_t)v * 16 + c] = ls;
        d_out[(size_t)n * 16 + 1 + (size_t)v * 16 + c] = o;
    }
}

// ---------------------------------------------------------------- launch
extern "C" void kernel_launch(void* const* d_in, const int* in_sizes, int n_in,
                              void* d_out, int out_size, void* d_ws, size_t ws_size,
                              hipStream_t stream) {
    const float* x     = (const float*)d_in[0];
    const int*   nb    = (const int*)d_in[1];
    const float* pca_w = (const float*)d_in[2];
    const float* pca_b = (const float*)d_in[3];
    const float* ln_g  = (const float*)d_in[4];
    const float* ln_b  = (const float*)d_in[5];
    const float* w_qs  = (const float*)d_in[6];
    const float* w_ks  = (const float*)d_in[7];
    const float* mlp_w = (const float*)d_in[8];
    const float* mlp_b = (const float*)d_in[9];
    float* out = (float*)d_out;

    const int d = 128;
    const int nfeat = in_sizes[2] / d;      // 500
    const int n = in_sizes[0] / nfeat;      // 20000
    const int npart = (n + 1) / 2;          // attn_prep block count

    float* bufA = (float*)d_ws;                       // n*128   : h, later u1
    float* bufB = bufA + (size_t)n * d;               // (n+1)*128 : xc0; amax overlays (xc0 dead)
    float* bufC = bufB + (size_t)(n + 1) * d;         // (n+1)*128 : xc1
    float* acc  = bufC + (size_t)(n + 1) * d;         // 1 float : attn loss sum
    int* amax = (int*)bufB;
    // attn partials overlay the head of bufC: consumed by reduce_kernel
    // before routing<false> writes bufC; row n untouched.
    float* partial = bufC;

    init_kernel<<<1, 256, 0, stream>>>(bufB, bufC, n);
    pca_gemm<<<(n + 31) / 32, 256, 0, stream>>>(x, pca_w, pca_b, bufA, n, nfeat);
    attn_prep<<<npart, 256, 0, stream>>>(bufA, ln_g, ln_b, w_qs, w_ks, bufB, partial, n);
    reduce_kernel<<<1, 256, 0, stream>>>(partial, acc, npart);
    routing_kernel<false><<<n, 256, 0, stream>>>(bufB, nb, bufC, nullptr, n);
    routing_kernel<true><<<n, 256, 0, stream>>>(bufC, nb, bufA, amax, n);
    meta_kernel<<<(n + 15) / 16, 256, 0, stream>>>(bufA, bufC, nb, amax, mlp_w, mlp_b, acc, out, n);
}